// Round 8
// baseline (208.895 us; speedup 1.0000x reference)
//
#include <hip/hip_runtime.h>
#include <hip/hip_bf16.h>

#define NROWS 16384
#define DIN   4096
#define DOUT  4096
#define RNK   64
#define EPSF  1e-7f

typedef float  f32x4  __attribute__((ext_vector_type(4)));
typedef __bf16 bf16x4 __attribute__((ext_vector_type(4)));
typedef __bf16 bf16x8 __attribute__((ext_vector_type(8)));

__device__ __forceinline__ bf16x8 cvt8(f32x4 a, f32x4 b) {
    bf16x8 r;
    r[0]=(__bf16)a.x; r[1]=(__bf16)a.y; r[2]=(__bf16)a.z; r[3]=(__bf16)a.w;
    r[4]=(__bf16)b.x; r[5]=(__bf16)b.y; r[6]=(__bf16)b.z; r[7]=(__bf16)b.w;
    return r;
}
__device__ __forceinline__ bf16x4 cvt4(f32x4 v) {
    bf16x4 r;
    r[0]=(__bf16)v.x; r[1]=(__bf16)v.y; r[2]=(__bf16)v.z; r[3]=(__bf16)v.w;
    return r;
}

// ---------------------------------------------------------------------------
// KA: Apf = Aw in bf16 MFMA-fragment order.
// Chunk (kt, ng, l): Apf[(kt*4+ng)*512 + l*8 + j] = Aw[ng*16+(l&15)][kt*32+(l>>4)*8+j]
// ---------------------------------------------------------------------------
__global__ __launch_bounds__(512, 2)
void ka_apf(const float* __restrict__ Aw, __bf16* __restrict__ Apf) {
    const int kt = blockIdx.x;           // 128 k-steps
    const int t = threadIdx.x;
    const int ng = t >> 7, le = (t >> 1) & 63, h = t & 1;
    f32x4 v = *(const f32x4*)&Aw[(size_t)(ng*16 + (le&15)) * DIN + kt*32 + (le>>4)*8 + h*4];
    *(bf16x4*)&Apf[((size_t)(kt*4 + ng))*512 + le*8 + h*4] = cvt4(v);
}

// ---------------------------------------------------------------------------
// KB: per-256-row B slice: bf16-convert, emit Bpf in MFMA-fragment order,
//     and Gram partials (G = B^T B, symmetric).
// ---------------------------------------------------------------------------
__global__ __launch_bounds__(512, 4)
void kb_gram(const float* __restrict__ Bw, __bf16* __restrict__ Bpf,
             float* __restrict__ Gpart) {
    __shared__ __bf16 bs[256][72];
    const int t = threadIdx.x;
    const int jb = blockIdx.x * 256;

    {   // stage + convert: thread t -> row t>>1, cols (t&1)*32..+31
        const int j0 = t >> 1, c0 = (t & 1) * 32;
        #pragma unroll
        for (int u = 0; u < 4; ++u) {
            f32x4 v0 = *(const f32x4*)&Bw[(size_t)(jb + j0) * RNK + c0 + 8*u];
            f32x4 v1 = *(const f32x4*)&Bw[(size_t)(jb + j0) * RNK + c0 + 8*u + 4];
            *(bf16x8*)&bs[j0][c0 + 8*u] = cvt8(v0, v1);
        }
    }
    __syncthreads();

    // fragment-order write-back
    #pragma unroll
    for (int u = 0; u < 4; ++u) {
        const int lc = t + 512 * u;
        const int ll = lc & 63;
        const int ks = (lc >> 6) & 1;
        const int jl = lc >> 7;
        bf16x8 v = *(const bf16x8*)&bs[jl * 16 + (ll & 15)][ks * 32 + (ll >> 4) * 8];
        const size_t C = ((size_t)((jb >> 4) + jl) * 2 + ks) * 64 + ll;
        *(bf16x8*)&Bpf[C * 8] = v;
    }

    // Gram partial
    const int r = t & 63, rp = (t >> 6) * 8;
    float acc[8] = {0,0,0,0,0,0,0,0};
    for (int j = 0; j < 256; ++j) {
        float s = (float)bs[j][r];
        bf16x8 v = *(const bf16x8*)&bs[j][rp];
        #pragma unroll
        for (int u = 0; u < 8; ++u) acc[u] += s * (float)v[u];
    }
    #pragma unroll
    for (int u = 0; u < 8; ++u)
        Gpart[(size_t)blockIdx.x * 4096 + r * 64 + rp + u] = acc[u];
}

__global__ void kc0_sum(const float* __restrict__ Gpart, float* __restrict__ G) {
    const int t = threadIdx.x;
    #pragma unroll
    for (int v = 0; v < 4; ++v) {
        f32x4 a = {0.f, 0.f, 0.f, 0.f};
        for (int b = 0; b < 16; ++b)
            a += *(const f32x4*)&Gpart[(size_t)b * 4096 + t * 16 + v * 4];
        *(f32x4*)&G[t * 16 + v * 4] = a;
    }
}

// ---------------------------------------------------------------------------
// Fused main kernel: 16 rows per block, 256 thr (4 waves), 1024 blocks.
// Phase 1: streaming GEMM1, waves split K 4-ways, zero barriers in loop.
// Epilogue: reduce partials -> sinh -> r2 = s1^T G s1 -> g -> s1pf frags
//           in LDS (overlaid on dead part[]).
// Phase 2: streaming GEMM2, zero barriers: Bpf frags from L2, dwordx4 stores.
// LDS 38.4 KB -> 4 blocks/CU (16 waves/CU); VGPR cap 128 (launch_bounds 256,4).
// ---------------------------------------------------------------------------
__global__ __launch_bounds__(256, 4)
void kfused(const float* __restrict__ x, const __bf16* __restrict__ Apf,
            const float* __restrict__ G, const __bf16* __restrict__ Bpf,
            float* __restrict__ out) {
    __shared__ __align__(16) char smem[38464];
    float (*part)[16][68] = (float (*)[16][68])(smem);            // 17408 B
    float (*Gs)[64]       = (float (*)[64])(smem + 17408);        // 16384 B
    float (*s1s)[68]      = (float (*)[68])(smem + 33792);        // 4352 B
    float (*ssqs)[16]     = (float (*)[16])(smem + 38144);        // 256 B
    float *gsl            = (float*)(smem + 38400);               // 64 B
    // s1pf overlays part[] (dead after the reduce, separated by 2 barriers)
    __bf16 (*s1pf)[64][8] = (__bf16 (*)[64][8])(smem);            // 2048 B

    const int t = threadIdx.x, l = t & 63, w = t >> 6;
    const int brow = blockIdx.x * 16;
    const int rl = l & 15, ko = l >> 4;

    // ---- phase 1: GEMM1 (k1-proven) ----
    const size_t xoff = (size_t)(brow + rl) * DIN + (size_t)w * 1024 + ko * 8;
    const size_t aoff = (size_t)(w * 32) * 2048 + (size_t)l * 8;

    f32x4 acc0 = {0,0,0,0}, acc1 = {0,0,0,0}, acc2 = {0,0,0,0}, acc3 = {0,0,0,0};
    float ssq = 0.f;

    f32x4 xc0 = *(const f32x4*)&x[xoff];
    f32x4 xc1 = *(const f32x4*)&x[xoff + 4];
    bf16x8 a0 = *(const bf16x8*)&Apf[aoff];
    bf16x8 a1 = *(const bf16x8*)&Apf[aoff + 512];
    bf16x8 a2 = *(const bf16x8*)&Apf[aoff + 1024];
    bf16x8 a3 = *(const bf16x8*)&Apf[aoff + 1536];

    #pragma unroll
    for (int i = 0; i < 32; ++i) {
        f32x4 xn0 = xc0, xn1 = xc1;
        bf16x8 b0 = a0, b1 = a1, b2 = a2, b3 = a3;
        if (i < 31) {
            xn0 = *(const f32x4*)&x[xoff + (i+1)*32];
            xn1 = *(const f32x4*)&x[xoff + (i+1)*32 + 4];
            const size_t ao = aoff + (size_t)(i+1)*2048;
            b0 = *(const bf16x8*)&Apf[ao];
            b1 = *(const bf16x8*)&Apf[ao + 512];
            b2 = *(const bf16x8*)&Apf[ao + 1024];
            b3 = *(const bf16x8*)&Apf[ao + 1536];
        }
        ssq += xc0.x*xc0.x + xc0.y*xc0.y + xc0.z*xc0.z + xc0.w*xc0.w;
        ssq += xc1.x*xc1.x + xc1.y*xc1.y + xc1.z*xc1.z + xc1.w*xc1.w;
        bf16x8 xf = cvt8(xc0, xc1);
        acc0 = __builtin_amdgcn_mfma_f32_16x16x32_bf16(a0, xf, acc0, 0, 0, 0);
        acc1 = __builtin_amdgcn_mfma_f32_16x16x32_bf16(a1, xf, acc1, 0, 0, 0);
        acc2 = __builtin_amdgcn_mfma_f32_16x16x32_bf16(a2, xf, acc2, 0, 0, 0);
        acc3 = __builtin_amdgcn_mfma_f32_16x16x32_bf16(a3, xf, acc3, 0, 0, 0);
        xc0 = xn0; xc1 = xn1; a0 = b0; a1 = b1; a2 = b2; a3 = b3;
    }

    // dump wave partials + ssq; stage G (L2 hit) concurrently
    *(f32x4*)&part[w][rl][ 0 + ko*4] = acc0;
    *(f32x4*)&part[w][rl][16 + ko*4] = acc1;
    *(f32x4*)&part[w][rl][32 + ko*4] = acc2;
    *(f32x4*)&part[w][rl][48 + ko*4] = acc3;
    ssq += __shfl_xor(ssq, 16);
    ssq += __shfl_xor(ssq, 32);
    if (l < 16) ssqs[w][l] = ssq;
    {
        float* gf = &Gs[0][0];
        const float* gp = &G[t * 16];
        *(f32x4*)&gf[t*16 + 0]  = *(const f32x4*)&gp[0];
        *(f32x4*)&gf[t*16 + 4]  = *(const f32x4*)&gp[4];
        *(f32x4*)&gf[t*16 + 8]  = *(const f32x4*)&gp[8];
        *(f32x4*)&gf[t*16 + 12] = *(const f32x4*)&gp[12];
    }
    __syncthreads();

    // reduce 4 wave-partials + sinh scale; thread t: row t>>4, cols (t&15)*4..+3
    const int row = t >> 4, c4 = (t & 15) * 4;
    f32x4 s = *(const f32x4*)&part[0][row][c4];
    s += *(const f32x4*)&part[1][row][c4];
    s += *(const f32x4*)&part[2][row][c4];
    s += *(const f32x4*)&part[3][row][c4];
    const float ssqt = ssqs[0][row] + ssqs[1][row] + ssqs[2][row] + ssqs[3][row];
    const float vn = fmaxf(sqrtf(ssqt), EPSF);
    const float sc = sinhf(vn) / vn;
    s *= sc;
    *(f32x4*)&s1s[row][c4] = s;
    __syncthreads();

    // r2 = s1^T G s1 (G symmetric)
    f32x4 yacc = {0,0,0,0};
    for (int j = 0; j < 64; ++j) {
        const float sj = s1s[row][j];
        yacc += *(const f32x4*)&Gs[j][c4] * sj;
    }
    float r2p = s.x*yacc.x + s.y*yacc.y + s.z*yacc.z + s.w*yacc.w;
    r2p += __shfl_xor(r2p, 1);
    r2p += __shfl_xor(r2p, 2);
    r2p += __shfl_xor(r2p, 4);
    r2p += __shfl_xor(r2p, 8);
    if ((t & 15) == 0) {
        const float r2 = r2p;
        const float rn = sqrtf(r2);
        gsl[row] = 0.25f * acoshf(fmaxf(sqrtf(1.f + r2), 1.f + EPSF))
                         / fmaxf(rn, EPSF);   // ALPHA/RANK = 0.25
    }
    __syncthreads();

    // build s1pf fragments in LDS (g folded in); overlays dead part[]
    if (t < 128) {
        const int le = t & 63, ks = t >> 6;
        const int er = le & 15, ec = ks * 32 + (le >> 4) * 8;
        const float g = gsl[er];
        bf16x8 p;
        #pragma unroll
        for (int u = 0; u < 8; ++u) p[u] = (__bf16)(g * s1s[er][ec + u]);
        *(bf16x8*)&s1pf[ks][le][0] = p;
    }
    __syncthreads();

    // ---- phase 2: GEMM2, barrier-free; wave w owns 16-col groups j=w*64..+63 ----
    {
        const bf16x8 sf0 = *(const bf16x8*)&s1pf[0][l][0];
        const bf16x8 sf1 = *(const bf16x8*)&s1pf[1][l][0];
        const size_t orow = (size_t)(brow + rl) * DOUT + ko * 4;
        #pragma unroll 4
        for (int jj = 0; jj < 64; ++jj) {
            const int j = w * 64 + jj;
            const size_t base = (size_t)j * 1024 + l * 8;
            bf16x8 b0 = *(const bf16x8*)&Bpf[base];
            bf16x8 b1 = *(const bf16x8*)&Bpf[base + 512];
            f32x4 a = {0.f, 0.f, 0.f, 0.f};
            a = __builtin_amdgcn_mfma_f32_16x16x32_bf16(b0, sf0, a, 0, 0, 0);
            a = __builtin_amdgcn_mfma_f32_16x16x32_bf16(b1, sf1, a, 0, 0, 0);
            *(f32x4*)&out[orow + (size_t)j * 16] = a;
        }
    }
}

extern "C" void kernel_launch(void* const* d_in, const int* in_sizes, int n_in,
                              void* d_out, int out_size, void* d_ws, size_t ws_size,
                              hipStream_t stream) {
    const float* x  = (const float*)d_in[0];   // (16384, 4096)
    const float* Aw = (const float*)d_in[1];   // (64, 4096)
    const float* Bw = (const float*)d_in[2];   // (4096, 64)
    float* out = (float*)d_out;

    char* ws = (char*)d_ws;
    __bf16* Apf   = (__bf16*)(ws);                  // 512 KB
    __bf16* Bpf   = (__bf16*)(ws + 0x080000);       // 512 KB
    float*  Gpart = (float*)(ws + 0x100000);        // 256 KB
    float*  G     = (float*)(ws + 0x140000);        // 16 KB

    ka_apf<<<128, 512, 0, stream>>>(Aw, Apf);
    kb_gram<<<16, 512, 0, stream>>>(Bw, Bpf, Gpart);
    kc0_sum<<<1, 256, 0, stream>>>(Gpart, G);
    kfused<<<NROWS / 16, 256, 0, stream>>>(x, Apf, G, Bpf, out);
}